// Round 12
// baseline (22.559 us; speedup 1.0000x reference)
//
#include <hip/hip_runtime.h>
#include <math.h>

// Problem constants: inputs (128, 64, 64, 32) fp32
#define BB 128
#define NN 64
#define DD 2048            // 64*32
#define ROWS (BB * NN)     // 8192
#define NBLK1 512          // 16 rows per block, 4 segments per batch
#define SEG 4

__device__ __forceinline__ float wave_reduce_sum_down(float v) {
    #pragma unroll
    for (int off = 32; off > 0; off >>= 1)
        v += __shfl_down(v, off, 64);
    return v;
}

// K1: 512 blocks x 512 threads (8 waves) -> 4 waves/SIMD for latency hiding.
// Each wave owns 2 rows; BOTH rows' 16 float4 loads issue before any compute
// (explicit pipeline). Sumsq via xor-butterfly (lane-uniform), inv, FMA into
// column accumulators. One 64 KB LDS combine at the end. Block 0 zeroes the
// K2 counter (kernel boundary = visibility fence).
__global__ __launch_bounds__(512, 4) void stream_kernel(
        const float* __restrict__ x,
        float* __restrict__ vseg,        // [512][2048]
        float* __restrict__ diag_seg,    // [512]
        unsigned* __restrict__ counter) {
    const int u = blockIdx.x;
    const int b = u >> 2, s = u & 3;     // batch, 16-row segment
    const int t = threadIdx.x;
    const int lane = t & 63, w = t >> 6; // 8 waves

    if (u == 0 && t == 0) *counter = 0;  // visible to K2 at kernel boundary

    const float* xw = x + ((size_t)b * NN + s * 16 + w * 2) * DD;
    const float4* p0 = reinterpret_cast<const float4*>(xw);
    const float4* p1 = reinterpret_cast<const float4*>(xw + DD);

    // issue ALL 16 loads up-front (16 independent float4 in flight per lane)
    float4 a0[8], a1[8];
    #pragma unroll
    for (int j = 0; j < 8; ++j) a0[j] = p0[lane + 64 * j];
    #pragma unroll
    for (int j = 0; j < 8; ++j) a1[j] = p1[lane + 64 * j];

    float4 acc[8];
    #pragma unroll
    for (int j = 0; j < 8; ++j) acc[j] = make_float4(0.f, 0.f, 0.f, 0.f);
    float diag = 0.f;                    // lane-uniform

    // row 0
    {
        float ss = 0.f;
        #pragma unroll
        for (int j = 0; j < 8; ++j)
            ss += a0[j].x * a0[j].x + a0[j].y * a0[j].y
                + a0[j].z * a0[j].z + a0[j].w * a0[j].w;
        #pragma unroll
        for (int off = 1; off < 64; off <<= 1)
            ss += __shfl_xor(ss, off, 64);
        const float inv = 1.0f / fmaxf(sqrtf(ss), 1e-12f);
        diag += ss * inv * inv;
        #pragma unroll
        for (int j = 0; j < 8; ++j) {
            acc[j].x = fmaf(a0[j].x, inv, acc[j].x);
            acc[j].y = fmaf(a0[j].y, inv, acc[j].y);
            acc[j].z = fmaf(a0[j].z, inv, acc[j].z);
            acc[j].w = fmaf(a0[j].w, inv, acc[j].w);
        }
    }
    // row 1
    {
        float ss = 0.f;
        #pragma unroll
        for (int j = 0; j < 8; ++j)
            ss += a1[j].x * a1[j].x + a1[j].y * a1[j].y
                + a1[j].z * a1[j].z + a1[j].w * a1[j].w;
        #pragma unroll
        for (int off = 1; off < 64; off <<= 1)
            ss += __shfl_xor(ss, off, 64);
        const float inv = 1.0f / fmaxf(sqrtf(ss), 1e-12f);
        diag += ss * inv * inv;
        #pragma unroll
        for (int j = 0; j < 8; ++j) {
            acc[j].x = fmaf(a1[j].x, inv, acc[j].x);
            acc[j].y = fmaf(a1[j].y, inv, acc[j].y);
            acc[j].z = fmaf(a1[j].z, inv, acc[j].z);
            acc[j].w = fmaf(a1[j].w, inv, acc[j].w);
        }
    }

    // cross-wave combine: [8][2048] floats = 64 KB LDS (2 blocks/CU fits 160)
    __shared__ float lds[8][DD];
    __shared__ float dl[8];
    float4* lw = reinterpret_cast<float4*>(lds[w]);
    #pragma unroll
    for (int j = 0; j < 8; ++j) lw[lane + 64 * j] = acc[j];
    if (lane == 0) dl[w] = diag;
    __syncthreads();

    // thread t -> float4 index t (byte 16t: conflict-free across waves' rows)
    float4 o = make_float4(0.f, 0.f, 0.f, 0.f);
    #pragma unroll
    for (int ww = 0; ww < 8; ++ww) {
        const float4 q = reinterpret_cast<const float4*>(lds[ww])[t];
        o.x += q.x; o.y += q.y; o.z += q.z; o.w += q.w;
    }
    reinterpret_cast<float4*>(vseg + (size_t)u * DD)[t] = o;
    if (t == 0)
        diag_seg[u] = dl[0] + dl[1] + dl[2] + dl[3]
                    + dl[4] + dl[5] + dl[6] + dl[7];
}

// K2: per-batch combine of SEG segment vectors + fence-free last-block tree.
__global__ __launch_bounds__(256) void combine_kernel(
        const float* __restrict__ vseg,
        const float* __restrict__ diag_seg,
        double* __restrict__ partials,   // [128]
        unsigned* __restrict__ counter,  // zeroed by K1
        float* __restrict__ out) {
    const int b = blockIdx.x;
    const int t = threadIdx.x;
    const int lane = t & 63, wid = t >> 6;   // 4 waves

    __shared__ float red[4];
    __shared__ int flag;
    __shared__ double sd[BB];

    float4 c0 = make_float4(0.f, 0.f, 0.f, 0.f);
    float4 c1 = make_float4(0.f, 0.f, 0.f, 0.f);
    #pragma unroll
    for (int o = 0; o < SEG; ++o) {
        const float4* src = reinterpret_cast<const float4*>(
            vseg + (size_t)(b * SEG + o) * DD);
        float4 q0 = src[t], q1 = src[t + 256];
        c0.x += q0.x; c0.y += q0.y; c0.z += q0.z; c0.w += q0.w;
        c1.x += q1.x; c1.y += q1.y; c1.z += q1.z; c1.w += q1.w;
    }
    float p = c0.x * c0.x + c0.y * c0.y + c0.z * c0.z + c0.w * c0.w
            + c1.x * c1.x + c1.y * c1.y + c1.z * c1.z + c1.w * c1.w;
    p = wave_reduce_sum_down(p);
    if (lane == 0) red[wid] = p;
    __syncthreads();

    if (t == 0) {
        double sp = (double)red[0] + (double)red[1]
                  + (double)red[2] + (double)red[3];
        double dp = 0.0;
        #pragma unroll
        for (int o = 0; o < SEG; ++o) dp += (double)diag_seg[b * SEG + o];
        __hip_atomic_store(&partials[b], sp - dp,
                           __ATOMIC_RELAXED, __HIP_MEMORY_SCOPE_AGENT);
        asm volatile("s_waitcnt vmcnt(0)" ::: "memory");   // drain my store
        unsigned old = __hip_atomic_fetch_add(counter, 1u,
                        __ATOMIC_RELAXED, __HIP_MEMORY_SCOPE_AGENT);
        flag = (old == (unsigned)(BB - 1)) ? 1 : 0;
    }
    __syncthreads();
    if (!flag) return;

    if (t < BB)
        sd[t] = __hip_atomic_load(&partials[t],
                        __ATOMIC_RELAXED, __HIP_MEMORY_SCOPE_AGENT);
    __syncthreads();
    #pragma unroll
    for (int off = BB / 2; off > 0; off >>= 1) {
        if (t < off) sd[t] += sd[t + off];
        __syncthreads();
    }
    if (t == 0) out[0] = (float)(sd[0] / (double)BB);
}

extern "C" void kernel_launch(void* const* d_in, const int* in_sizes, int n_in,
                              void* d_out, int out_size, void* d_ws, size_t ws_size,
                              hipStream_t stream) {
    const float* x = (const float*)d_in[0];
    float* out = (float*)d_out;
    char* ws = (char*)d_ws;

    const size_t vbytes = (size_t)NBLK1 * DD * 4;          // 4 MB
    float* vseg       = (float*)ws;
    float* diag_seg   = (float*)(ws + vbytes);             // 2 KB
    double* partials  = (double*)(ws + vbytes + 2048);     // 1 KB
    unsigned* counter = (unsigned*)(ws + vbytes + 2048 + 1024);

    stream_kernel<<<NBLK1, 512, 0, stream>>>(x, vseg, diag_seg, counter);
    combine_kernel<<<BB, 256, 0, stream>>>(vseg, diag_seg, partials,
                                           counter, out);
}